// Round 4
// baseline (209.921 us; speedup 1.0000x reference)
//
#include <hip/hip_runtime.h>
#include <hip/hip_bf16.h>
#include <math.h>

#define TSEQ 2048
#define CEMB 1024
#define NHEAD 16
#define HS 64

typedef __attribute__((ext_vector_type(8))) short bf16x8;
typedef __attribute__((ext_vector_type(4))) float f32x4;

__device__ __forceinline__ void gload16(const void* g, void* l) {
    __builtin_amdgcn_global_load_lds(
        (const __attribute__((address_space(1))) unsigned int*)g,
        (__attribute__((address_space(3))) unsigned int*)l, 16, 0, 0);
}

// swizzled LDS byte offset for [row][col] bf16 tiles with 128 B rows
#define SWZ(row, colb) (((((row) << 7) + (colb))) ^ (((row) & 7) << 4))

// ---------------- RoPE table ----------------
// Reference quirk: _apply_rope uses cache[:d1] where d1 = n_head after the
// transpose, so the rotation angle is head_index * theta_j (constant over t).
__global__ void rope_tbl_k(float* __restrict__ tbl) {
    int i = blockIdx.x * blockDim.x + threadIdx.x;
    if (i >= NHEAD * 32) return;
    int h = i >> 5, j = i & 31;
    double theta = pow(10000.0, -2.0 * (double)j / 1024.0);
    double ang = (double)h * theta;
    tbl[2 * i + 0] = (float)cos(ang);
    tbl[2 * i + 1] = (float)sin(ang);
}

// ---------------- fp32 -> bf16 convert (x) ----------------
__global__ __launch_bounds__(256) void cvt_bf16_k(const float* __restrict__ in,
                                                  __hip_bfloat16* __restrict__ out) {
    int i = (blockIdx.x * 256 + threadIdx.x) * 8;
    float4 a = *(const float4*)(in + i);
    float4 b = *(const float4*)(in + i + 4);
    union { bf16x8 v; __hip_bfloat16 h[8]; } pk;
    pk.h[0] = __float2bfloat16(a.x); pk.h[1] = __float2bfloat16(a.y);
    pk.h[2] = __float2bfloat16(a.z); pk.h[3] = __float2bfloat16(a.w);
    pk.h[4] = __float2bfloat16(b.x); pk.h[5] = __float2bfloat16(b.y);
    pk.h[6] = __float2bfloat16(b.z); pk.h[7] = __float2bfloat16(b.w);
    *(bf16x8*)(out + i) = pk.v;
}

// ---------------- transpose fp32 (K,N) -> bf16 (N,K) ----------------
__global__ __launch_bounds__(256) void transpose_bf16_k(const float* __restrict__ src,
                                                        __hip_bfloat16* __restrict__ dst,
                                                        int K, int N) {
    __shared__ float tile[32][33];
    int n0 = blockIdx.x * 32, k0 = blockIdx.y * 32;
    int tx = threadIdx.x & 31, ty = threadIdx.x >> 5;   // ty 0..7
#pragma unroll
    for (int i = 0; i < 32; i += 8)
        tile[ty + i][tx] = src[(size_t)(k0 + ty + i) * N + n0 + tx];
    __syncthreads();
#pragma unroll
    for (int i = 0; i < 32; i += 8)
        dst[(size_t)(n0 + ty + i) * K + k0 + tx] = __float2bfloat16(tile[tx][ty + i]);
}

// ---------------- QKV GEMM, bf16 MFMA, RoPE epilogue ----------------
// A = Xb (4096,1024) bf16 row-major; B = Wta (3072,1024) bf16 (pre-transposed).
// 128x128 tile, 4 waves (2x2), 4x4 16x16x32 frags, BK=32, global_load_lds w=16.
__global__ __launch_bounds__(256) void qkv_mfma_k(
    const __hip_bfloat16* __restrict__ Xb, const __hip_bfloat16* __restrict__ Wt,
    const float* __restrict__ bias, const float* __restrict__ tbl,
    __hip_bfloat16* __restrict__ Qb, __hip_bfloat16* __restrict__ Kb,
    __hip_bfloat16* __restrict__ Vtb)
{
    __shared__ __hip_bfloat16 Al[128 * 32];
    __shared__ __hip_bfloat16 Bl[128 * 32];
    const int tid = threadIdx.x;
    const int lane = tid & 63, w = tid >> 6;
    const int lr = lane & 15, lg = lane >> 4;
    const int wm = w >> 1, wn = w & 1;
    const int n0 = blockIdx.x * 128;   // 0..2944
    const int m0 = blockIdx.y * 128;   // 0..3968
    const __hip_bfloat16* gA = Xb + (size_t)(m0 + (tid >> 2)) * CEMB + (tid & 3) * 8;
    const __hip_bfloat16* gB = Wt + (size_t)(n0 + (tid >> 2)) * CEMB + (tid & 3) * 8;
    __hip_bfloat16* lA = &Al[tid * 8];
    __hip_bfloat16* lB = &Bl[tid * 8];
    f32x4 acc[4][4] = {};
    for (int k0 = 0; k0 < CEMB; k0 += 32) {
        if (k0) __syncthreads();
        gload16(gA + k0, lA);
        gload16(gA + 64 * CEMB + k0, lA + 2048);
        gload16(gB + k0, lB);
        gload16(gB + 64 * CEMB + k0, lB + 2048);
        __syncthreads();
        bf16x8 af[4], bfr[4];
#pragma unroll
        for (int mi = 0; mi < 4; ++mi)
            af[mi] = *(const bf16x8*)&Al[(wm * 64 + mi * 16 + lr) * 32 + lg * 8];
#pragma unroll
        for (int ni = 0; ni < 4; ++ni)
            bfr[ni] = *(const bf16x8*)&Bl[(wn * 64 + ni * 16 + lr) * 32 + lg * 8];
#pragma unroll
        for (int mi = 0; mi < 4; ++mi)
#pragma unroll
            for (int ni = 0; ni < 4; ++ni)
                acc[mi][ni] = __builtin_amdgcn_mfma_f32_16x16x32_bf16(af[mi], bfr[ni], acc[mi][ni], 0, 0, 0);
    }
    // epilogue: bias + rope + scatter. sec/bb uniform per block.
    const int sec = (n0 >> 10);
#pragma unroll
    for (int mi = 0; mi < 4; ++mi) {
#pragma unroll
        for (int ni = 0; ni < 4; ++ni) {
            const int gcol = n0 + wn * 64 + ni * 16 + lr;
            const int c63 = gcol & 63;
            const int h = (gcol & 1023) >> 6;
            const int j = c63 >> 1;
            const float cth = tbl[(h * 32 + j) * 2 + 0];
            const float sth = tbl[(h * 32 + j) * 2 + 1];
            const float bv = bias[gcol];
            const int growb = m0 + wm * 64 + mi * 16 + lg * 4;
            const int bb = growb >> 11;
            const int t0 = growb & 2047;
            if (sec == 2) {
                union { unsigned long long u; __hip_bfloat16 hh[4]; } pk;
#pragma unroll
                for (int r = 0; r < 4; ++r) pk.hh[r] = __float2bfloat16(acc[mi][ni][r] + bv);
                *(unsigned long long*)&Vtb[(((size_t)bb * NHEAD + h) * HS + c63) * TSEQ + t0] = pk.u;
            } else {
                // Q scale folds 1/sqrt(hs) AND log2(e) so attention can use exp2
                const float sc = (sec == 0) ? 0.18033688011112042f : 1.0f;
                __hip_bfloat16* dst = (sec == 0) ? Qb : Kb;
#pragma unroll
                for (int r = 0; r < 4; ++r) {
                    float val = acc[mi][ni][r] + bv;
                    float prt = __shfl_xor(val, 1);
                    float rot = (lr & 1) ? (val * cth + prt * sth) : (val * cth - prt * sth);
                    dst[(((size_t)bb * NHEAD + h) * TSEQ + t0 + r) * HS + c63] = __float2bfloat16(rot * sc);
                }
            }
        }
    }
}

// ---------------- Flash attention, bf16 MFMA ----------------
// LPT block order, reg-staged K/V prefetch (T14), XOR-swizzled K/V LDS (T2),
// ones-column MFMA row-sum, T13 skip-rescale (THR=0, bit-exact).
__global__ __launch_bounds__(256) void attn_k(
    const __hip_bfloat16* __restrict__ Q, const __hip_bfloat16* __restrict__ K,
    const __hip_bfloat16* __restrict__ Vt, __hip_bfloat16* __restrict__ Y)
{
    __shared__ __hip_bfloat16 KsBuf[64 * 64];    // [kv][hs], swizzled
    __shared__ __hip_bfloat16 VsBuf[64 * 64];    // [hs][kv], swizzled
    __shared__ __hip_bfloat16 Ps[4][16][72];     // per-wave P, [q][kv]
    char* KsB = (char*)KsBuf;
    char* VsB = (char*)VsBuf;
    const int tid = threadIdx.x;
    const int w = tid >> 6;
    const int lane = tid & 63;
    const int lr = lane & 15;
    const int lg = lane >> 4;
    const int qblk = 31 - blockIdx.x;            // LPT: longest blocks first
    const int bh = blockIdx.y;
    const size_t bho = (size_t)bh * TSEQ * HS;
    const int qw = qblk * 64 + w * 16;

    // staging: 512 16B-chunks; thread t owns chunks t and t+256
    const int kr0 = tid >> 3, kc0 = (tid & 7) * 8;
    const int kr1 = (tid + 256) >> 3, kc1 = (tid & 7) * 8;
    const int wz0 = SWZ(kr0, kc0 * 2), wz1 = SWZ(kr1, kc1 * 2);
    const __hip_bfloat16* Kg = K + bho;
    const __hip_bfloat16* Vg = Vt + bho;

    // prologue: load tile 0 into regs
    bf16x8 nk0 = *(const bf16x8*)(Kg + kr0 * HS + kc0);
    bf16x8 nk1 = *(const bf16x8*)(Kg + kr1 * HS + kc1);
    bf16x8 nv0 = *(const bf16x8*)(Vg + (size_t)kr0 * TSEQ + kc0);
    bf16x8 nv1 = *(const bf16x8*)(Vg + (size_t)kr1 * TSEQ + kc1);

    bf16x8 qa[2];
    {
        const __hip_bfloat16* qp = Q + bho + (size_t)(qw + lr) * HS + lg * 8;
        qa[0] = *(const bf16x8*)(qp);
        qa[1] = *(const bf16x8*)(qp + 32);
    }
    const bf16x8 ones = {0x3F80, 0x3F80, 0x3F80, 0x3F80, 0x3F80, 0x3F80, 0x3F80, 0x3F80};
    float mrow[4] = {-1e30f, -1e30f, -1e30f, -1e30f};
    f32x4 lacc = {};
    f32x4 o[4] = {};   // [ht]: col = ht*16+lr, row(q) = qw + lg*4 + r

    for (int kt = 0; kt <= qblk; ++kt) {
        __syncthreads();   // everyone done reading prev K/Vs
        *(bf16x8*)(KsB + wz0) = nk0;
        *(bf16x8*)(KsB + wz1) = nk1;
        *(bf16x8*)(VsB + wz0) = nv0;
        *(bf16x8*)(VsB + wz1) = nv1;
        if (kt < qblk) {   // issue next tile's loads; they fly under compute
            const __hip_bfloat16* kg = Kg + (size_t)(kt + 1) * 64 * HS;
            const __hip_bfloat16* vg = Vg + (size_t)(kt + 1) * 64;
            nk0 = *(const bf16x8*)(kg + kr0 * HS + kc0);
            nk1 = *(const bf16x8*)(kg + kr1 * HS + kc1);
            nv0 = *(const bf16x8*)(vg + (size_t)kr0 * TSEQ + kc0);
            nv1 = *(const bf16x8*)(vg + (size_t)kr1 * TSEQ + kc1);
        }
        __syncthreads();
        // S = Q K^T  (Q pre-scaled by 0.125*log2e)
        f32x4 s[4] = {};
#pragma unroll
        for (int ct = 0; ct < 4; ++ct) {
#pragma unroll
            for (int kb = 0; kb < 2; ++kb) {
                bf16x8 kf = *(const bf16x8*)(KsB + SWZ(ct * 16 + lr, kb * 64 + lg * 16));
                s[ct] = __builtin_amdgcn_mfma_f32_16x16x32_bf16(qa[kb], kf, s[ct], 0, 0, 0);
            }
        }
        if (kt == qblk) {
#pragma unroll
            for (int ct = 0; ct < 4; ++ct) {
                int col = kt * 64 + ct * 16 + lr;
#pragma unroll
                for (int r = 0; r < 4; ++r) {
                    if (col > qw + lg * 4 + r) s[ct][r] = -1e30f;
                }
            }
        }
        // online softmax (log2 domain); row r lives in 16 lanes (fixed lg)
#pragma unroll
        for (int r = 0; r < 4; ++r) {
            float mx = fmaxf(fmaxf(s[0][r], s[1][r]), fmaxf(s[2][r], s[3][r]));
            mx = fmaxf(mx, __shfl_xor(mx, 1));
            mx = fmaxf(mx, __shfl_xor(mx, 2));
            mx = fmaxf(mx, __shfl_xor(mx, 4));
            mx = fmaxf(mx, __shfl_xor(mx, 8));
            if (__ballot(mx > mrow[r])) {       // T13, THR=0: bit-exact skip
                float mn = fmaxf(mrow[r], mx);
                float alpha = exp2f(mrow[r] - mn);
                mrow[r] = mn;
                lacc[r] *= alpha;
                o[0][r] *= alpha; o[1][r] *= alpha; o[2][r] *= alpha; o[3][r] *= alpha;
            }
#pragma unroll
            for (int ct = 0; ct < 4; ++ct) {
                float p = exp2f(s[ct][r] - mrow[r]);
                Ps[w][lg * 4 + r][ct * 16 + lr] = __float2bfloat16(p);
            }
        }
        // PV + row-sum via ones-column (wave-internal LDS RAW, in-order)
#pragma unroll
        for (int kc = 0; kc < 2; ++kc) {
            bf16x8 pa = *(const bf16x8*)&Ps[w][lr][kc * 32 + lg * 8];
            lacc = __builtin_amdgcn_mfma_f32_16x16x32_bf16(pa, ones, lacc, 0, 0, 0);
#pragma unroll
            for (int ht = 0; ht < 4; ++ht) {
                bf16x8 vb = *(const bf16x8*)(VsB + SWZ(ht * 16 + lr, kc * 64 + lg * 16));
                o[ht] = __builtin_amdgcn_mfma_f32_16x16x32_bf16(pa, vb, o[ht], 0, 0, 0);
            }
        }
    }
    const int b = bh >> 4, h = bh & 15;
#pragma unroll
    for (int r = 0; r < 4; ++r) {
        float inv = 1.f / lacc[r];
        int q = qw + lg * 4 + r;
        __hip_bfloat16* yp = Y + ((size_t)b * TSEQ + q) * CEMB + h * HS + lr;
#pragma unroll
        for (int ht = 0; ht < 4; ++ht) yp[ht * 16] = __float2bfloat16(o[ht][r] * inv);
    }
}

// ---------------- Output projection, bf16 MFMA ----------------
__global__ __launch_bounds__(256) void proj_mfma_k(
    const __hip_bfloat16* __restrict__ Ab, const __hip_bfloat16* __restrict__ Wt,
    const float* __restrict__ bias, float* __restrict__ out)
{
    __shared__ __hip_bfloat16 Al[128 * 32];
    __shared__ __hip_bfloat16 Bl[128 * 32];
    const int tid = threadIdx.x;
    const int lane = tid & 63, w = tid >> 6;
    const int lr = lane & 15, lg = lane >> 4;
    const int wm = w >> 1, wn = w & 1;
    const int n0 = blockIdx.x * 128;
    const int m0 = blockIdx.y * 128;
    const __hip_bfloat16* gA = Ab + (size_t)(m0 + (tid >> 2)) * CEMB + (tid & 3) * 8;
    const __hip_bfloat16* gB = Wt + (size_t)(n0 + (tid >> 2)) * CEMB + (tid & 3) * 8;
    __hip_bfloat16* lA = &Al[tid * 8];
    __hip_bfloat16* lB = &Bl[tid * 8];
    f32x4 acc[4][4] = {};
    for (int k0 = 0; k0 < CEMB; k0 += 32) {
        if (k0) __syncthreads();
        gload16(gA + k0, lA);
        gload16(gA + 64 * CEMB + k0, lA + 2048);
        gload16(gB + k0, lB);
        gload16(gB + 64 * CEMB + k0, lB + 2048);
        __syncthreads();
        bf16x8 af[4], bfr[4];
#pragma unroll
        for (int mi = 0; mi < 4; ++mi)
            af[mi] = *(const bf16x8*)&Al[(wm * 64 + mi * 16 + lr) * 32 + lg * 8];
#pragma unroll
        for (int ni = 0; ni < 4; ++ni)
            bfr[ni] = *(const bf16x8*)&Bl[(wn * 64 + ni * 16 + lr) * 32 + lg * 8];
#pragma unroll
        for (int mi = 0; mi < 4; ++mi)
#pragma unroll
            for (int ni = 0; ni < 4; ++ni)
                acc[mi][ni] = __builtin_amdgcn_mfma_f32_16x16x32_bf16(af[mi], bfr[ni], acc[mi][ni], 0, 0, 0);
    }
#pragma unroll
    for (int mi = 0; mi < 4; ++mi) {
#pragma unroll
        for (int ni = 0; ni < 4; ++ni) {
            const int gcol = n0 + wn * 64 + ni * 16 + lr;
            const float bv = bias[gcol];
            const int growb = m0 + wm * 64 + mi * 16 + lg * 4;
#pragma unroll
            for (int r = 0; r < 4; ++r)
                out[(size_t)(growb + r) * CEMB + gcol] = acc[mi][ni][r] + bv;
        }
    }
}

extern "C" void kernel_launch(void* const* d_in, const int* in_sizes, int n_in,
                              void* d_out, int out_size, void* d_ws, size_t ws_size,
                              hipStream_t stream)
{
    const float* x      = (const float*)d_in[0];
    const float* w_attn = (const float*)d_in[1];
    const float* b_attn = (const float*)d_in[2];
    const float* w_proj = (const float*)d_in[3];
    const float* b_proj = (const float*)d_in[4];
    float* out = (float*)d_out;
    char* base = (char*)d_ws;

    const size_t MB = 1048576;
    float* tbl          = (float*)base;                         // 4 KB
    __hip_bfloat16* Xb  = (__hip_bfloat16*)(base + 4096);       // 8 MB (reused as Yb)
    __hip_bfloat16* Wta = (__hip_bfloat16*)(base + 4096 + 8 * MB);   // 6 MB
    __hip_bfloat16* Wpt = (__hip_bfloat16*)(base + 4096 + 14 * MB);  // 2 MB
    __hip_bfloat16* Qb  = (__hip_bfloat16*)(base + 4096 + 16 * MB);  // 8 MB
    __hip_bfloat16* Kb  = (__hip_bfloat16*)(base + 4096 + 24 * MB);  // 8 MB
    __hip_bfloat16* Vtb = (__hip_bfloat16*)(base + 4096 + 32 * MB);  // 8 MB
    __hip_bfloat16* Yb  = Xb;   // x no longer needed after qkv GEMM

    rope_tbl_k<<<1, 512, 0, stream>>>(tbl);
    cvt_bf16_k<<<2048, 256, 0, stream>>>(x, Xb);
    transpose_bf16_k<<<dim3(96, 32), 256, 0, stream>>>(w_attn, Wta, CEMB, 3 * CEMB);
    transpose_bf16_k<<<dim3(32, 32), 256, 0, stream>>>(w_proj, Wpt, CEMB, CEMB);
    qkv_mfma_k<<<dim3(24, 32), 256, 0, stream>>>(Xb, Wta, b_attn, tbl, Qb, Kb, Vtb);
    attn_k<<<dim3(32, 32), 256, 0, stream>>>(Qb, Kb, Vtb, Yb);
    proj_mfma_k<<<dim3(8, 32), 256, 0, stream>>>(Yb, Wpt, b_proj, out);
}

// Round 5
// 155.771 us; speedup vs baseline: 1.3476x; 1.3476x over previous
//
#include <hip/hip_runtime.h>
#include <hip/hip_bf16.h>
#include <math.h>

#define TSEQ 2048
#define CEMB 1024
#define NHEAD 16
#define HS 64

typedef __attribute__((ext_vector_type(8))) short bf16x8;
typedef __attribute__((ext_vector_type(4))) float f32x4;

__device__ __forceinline__ void gload16(const void* g, void* l) {
    __builtin_amdgcn_global_load_lds(
        (const __attribute__((address_space(1))) unsigned int*)g,
        (__attribute__((address_space(3))) unsigned int*)l, 16, 0, 0);
}

// swizzled LDS byte offset for [row][col] bf16 tiles with 128 B rows
#define SWZ(row, colb) (((((row) << 7) + (colb))) ^ (((row) & 7) << 4))

// ---------------- RoPE table ----------------
// Reference quirk: _apply_rope uses cache[:d1] where d1 = n_head after the
// transpose, so the rotation angle is head_index * theta_j (constant over t).
__global__ void rope_tbl_k(float* __restrict__ tbl) {
    int i = blockIdx.x * blockDim.x + threadIdx.x;
    if (i >= NHEAD * 32) return;
    int h = i >> 5, j = i & 31;
    double theta = pow(10000.0, -2.0 * (double)j / 1024.0);
    double ang = (double)h * theta;
    tbl[2 * i + 0] = (float)cos(ang);
    tbl[2 * i + 1] = (float)sin(ang);
}

// ---------------- fp32 -> bf16 convert (x) ----------------
__global__ __launch_bounds__(256) void cvt_bf16_k(const float* __restrict__ in,
                                                  __hip_bfloat16* __restrict__ out) {
    int i = (blockIdx.x * 256 + threadIdx.x) * 8;
    float4 a = *(const float4*)(in + i);
    float4 b = *(const float4*)(in + i + 4);
    union { bf16x8 v; __hip_bfloat16 h[8]; } pk;
    pk.h[0] = __float2bfloat16(a.x); pk.h[1] = __float2bfloat16(a.y);
    pk.h[2] = __float2bfloat16(a.z); pk.h[3] = __float2bfloat16(a.w);
    pk.h[4] = __float2bfloat16(b.x); pk.h[5] = __float2bfloat16(b.y);
    pk.h[6] = __float2bfloat16(b.z); pk.h[7] = __float2bfloat16(b.w);
    *(bf16x8*)(out + i) = pk.v;
}

// ---------------- transpose fp32 (K,N) -> bf16 (N,K) ----------------
__global__ __launch_bounds__(256) void transpose_bf16_k(const float* __restrict__ src,
                                                        __hip_bfloat16* __restrict__ dst,
                                                        int K, int N) {
    __shared__ float tile[32][33];
    int n0 = blockIdx.x * 32, k0 = blockIdx.y * 32;
    int tx = threadIdx.x & 31, ty = threadIdx.x >> 5;   // ty 0..7
#pragma unroll
    for (int i = 0; i < 32; i += 8)
        tile[ty + i][tx] = src[(size_t)(k0 + ty + i) * N + n0 + tx];
    __syncthreads();
#pragma unroll
    for (int i = 0; i < 32; i += 8)
        dst[(size_t)(n0 + ty + i) * K + k0 + tx] = __float2bfloat16(tile[tx][ty + i]);
}

// ---------------- QKV GEMM, bf16 MFMA, RoPE epilogue ----------------
// A = Xb (4096,1024) bf16 row-major; B = Wta (3072,1024) bf16 (pre-transposed).
// 128x128 tile, 4 waves (2x2), 4x4 16x16x32 frags, BK=32, global_load_lds w=16.
__global__ __launch_bounds__(256) void qkv_mfma_k(
    const __hip_bfloat16* __restrict__ Xb, const __hip_bfloat16* __restrict__ Wt,
    const float* __restrict__ bias, const float* __restrict__ tbl,
    __hip_bfloat16* __restrict__ Qb, __hip_bfloat16* __restrict__ Kb,
    __hip_bfloat16* __restrict__ Vtb)
{
    __shared__ __hip_bfloat16 Al[128 * 32];
    __shared__ __hip_bfloat16 Bl[128 * 32];
    const int tid = threadIdx.x;
    const int lane = tid & 63, w = tid >> 6;
    const int lr = lane & 15, lg = lane >> 4;
    const int wm = w >> 1, wn = w & 1;
    const int n0 = blockIdx.x * 128;   // 0..2944
    const int m0 = blockIdx.y * 128;   // 0..3968
    const __hip_bfloat16* gA = Xb + (size_t)(m0 + (tid >> 2)) * CEMB + (tid & 3) * 8;
    const __hip_bfloat16* gB = Wt + (size_t)(n0 + (tid >> 2)) * CEMB + (tid & 3) * 8;
    __hip_bfloat16* lA = &Al[tid * 8];
    __hip_bfloat16* lB = &Bl[tid * 8];
    f32x4 acc[4][4] = {};
    for (int k0 = 0; k0 < CEMB; k0 += 32) {
        if (k0) __syncthreads();
        gload16(gA + k0, lA);
        gload16(gA + 64 * CEMB + k0, lA + 2048);
        gload16(gB + k0, lB);
        gload16(gB + 64 * CEMB + k0, lB + 2048);
        __syncthreads();
        bf16x8 af[4], bfr[4];
#pragma unroll
        for (int mi = 0; mi < 4; ++mi)
            af[mi] = *(const bf16x8*)&Al[(wm * 64 + mi * 16 + lr) * 32 + lg * 8];
#pragma unroll
        for (int ni = 0; ni < 4; ++ni)
            bfr[ni] = *(const bf16x8*)&Bl[(wn * 64 + ni * 16 + lr) * 32 + lg * 8];
#pragma unroll
        for (int mi = 0; mi < 4; ++mi)
#pragma unroll
            for (int ni = 0; ni < 4; ++ni)
                acc[mi][ni] = __builtin_amdgcn_mfma_f32_16x16x32_bf16(af[mi], bfr[ni], acc[mi][ni], 0, 0, 0);
    }
    // epilogue: bias + rope + scatter. sec/bb uniform per block.
    const int sec = (n0 >> 10);
#pragma unroll
    for (int mi = 0; mi < 4; ++mi) {
#pragma unroll
        for (int ni = 0; ni < 4; ++ni) {
            const int gcol = n0 + wn * 64 + ni * 16 + lr;
            const int c63 = gcol & 63;
            const int h = (gcol & 1023) >> 6;
            const int j = c63 >> 1;
            const float cth = tbl[(h * 32 + j) * 2 + 0];
            const float sth = tbl[(h * 32 + j) * 2 + 1];
            const float bv = bias[gcol];
            const int growb = m0 + wm * 64 + mi * 16 + lg * 4;
            const int bb = growb >> 11;
            const int t0 = growb & 2047;
            if (sec == 2) {
                union { unsigned long long u; __hip_bfloat16 hh[4]; } pk;
#pragma unroll
                for (int r = 0; r < 4; ++r) pk.hh[r] = __float2bfloat16(acc[mi][ni][r] + bv);
                *(unsigned long long*)&Vtb[(((size_t)bb * NHEAD + h) * HS + c63) * TSEQ + t0] = pk.u;
            } else {
                // Q scale folds 1/sqrt(hs) AND log2(e) so attention can use exp2
                const float sc = (sec == 0) ? 0.18033688011112042f : 1.0f;
                __hip_bfloat16* dst = (sec == 0) ? Qb : Kb;
#pragma unroll
                for (int r = 0; r < 4; ++r) {
                    float val = acc[mi][ni][r] + bv;
                    float prt = __shfl_xor(val, 1);
                    float rot = (lr & 1) ? (val * cth + prt * sth) : (val * cth - prt * sth);
                    dst[(((size_t)bb * NHEAD + h) * TSEQ + t0 + r) * HS + c63] = __float2bfloat16(rot * sc);
                }
            }
        }
    }
}

// ---------------- Flash attention, bf16 MFMA ----------------
// Flat 1D grid: bh = id&31 (CU-balance + per-XCD K/V locality), qblk = id>>5.
// K/V staged via global_load_lds with pre-swizzled SOURCE (linear LDS dest,
// swizzled read = T21-consistent). Ones-column MFMA row-sum, T13 skip-rescale.
__global__ __launch_bounds__(256) void attn_k(
    const __hip_bfloat16* __restrict__ Q, const __hip_bfloat16* __restrict__ K,
    const __hip_bfloat16* __restrict__ Vt, __hip_bfloat16* __restrict__ Y)
{
    __shared__ __hip_bfloat16 KsBuf[64 * 64];    // [kv][hs], swizzled storage
    __shared__ __hip_bfloat16 VsBuf[64 * 64];    // [hs][kv], swizzled storage
    __shared__ __hip_bfloat16 Ps[4][16][72];     // per-wave P, [q][kv]
    char* KsB = (char*)KsBuf;
    char* VsB = (char*)VsBuf;
    const int tid = threadIdx.x;
    const int w = tid >> 6;
    const int lane = tid & 63;
    const int lr = lane & 15;
    const int lg = lane >> 4;
    const int id = blockIdx.x;
    const int bh = id & 31;          // fast dim: decorrelates qblk from CU
    const int qblk = id >> 5;
    const size_t bho = (size_t)bh * TSEQ * HS;
    const int qw = qblk * 64 + w * 16;

    // staging: 512 16B chunks per tile; thread t owns chunks t and t+256.
    // LDS dest is linear (chunk c at byte c*16); global source is the chunk
    // that belongs there under the XOR swizzle (bits 4-6 ^= rowbits 7-9).
    const __hip_bfloat16* Kg = K + bho;
    const __hip_bfloat16* Vg = Vt + bho;
    int ko0, ko1, vo0, vo1;
    {
        int o0 = tid * 16, o1 = o0 + 4096;
        int L0 = o0 ^ (((o0 >> 7) & 7) << 4);
        int L1 = o1 ^ (((o1 >> 7) & 7) << 4);
        ko0 = (L0 >> 7) * HS + ((L0 & 127) >> 1);
        ko1 = (L1 >> 7) * HS + ((L1 & 127) >> 1);
        vo0 = (L0 >> 7) * TSEQ + ((L0 & 127) >> 1);
        vo1 = (L1 >> 7) * TSEQ + ((L1 & 127) >> 1);
    }

    bf16x8 qa[2];
    {
        const __hip_bfloat16* qp = Q + bho + (size_t)(qw + lr) * HS + lg * 8;
        qa[0] = *(const bf16x8*)(qp);
        qa[1] = *(const bf16x8*)(qp + 32);
    }
    const bf16x8 ones = {0x3F80, 0x3F80, 0x3F80, 0x3F80, 0x3F80, 0x3F80, 0x3F80, 0x3F80};
    float mrow[4] = {-1e30f, -1e30f, -1e30f, -1e30f};
    f32x4 lacc = {};
    f32x4 o[4] = {};   // [ht]: col = ht*16+lr, row(q) = qw + lg*4 + r

    for (int kt = 0; kt <= qblk; ++kt) {
        __syncthreads();   // everyone done reading prev K/Vs
        {
            const __hip_bfloat16* kg = Kg + (size_t)kt * 64 * HS;
            const __hip_bfloat16* vg = Vg + (size_t)kt * 64;
            gload16(kg + ko0, KsB + tid * 16);
            gload16(kg + ko1, KsB + 4096 + tid * 16);
            gload16(vg + vo0, VsB + tid * 16);
            gload16(vg + vo1, VsB + 4096 + tid * 16);
        }
        __syncthreads();
        // S = Q K^T  (Q pre-scaled by 0.125*log2e)
        f32x4 s[4] = {};
#pragma unroll
        for (int ct = 0; ct < 4; ++ct) {
#pragma unroll
            for (int kb = 0; kb < 2; ++kb) {
                bf16x8 kf = *(const bf16x8*)(KsB + SWZ(ct * 16 + lr, kb * 64 + lg * 16));
                s[ct] = __builtin_amdgcn_mfma_f32_16x16x32_bf16(qa[kb], kf, s[ct], 0, 0, 0);
            }
        }
        if (kt == qblk) {
#pragma unroll
            for (int ct = 0; ct < 4; ++ct) {
                int col = kt * 64 + ct * 16 + lr;
#pragma unroll
                for (int r = 0; r < 4; ++r) {
                    if (col > qw + lg * 4 + r) s[ct][r] = -1e30f;
                }
            }
        }
        // online softmax (log2 domain); row r lives in 16 lanes (fixed lg)
#pragma unroll
        for (int r = 0; r < 4; ++r) {
            float mx = fmaxf(fmaxf(s[0][r], s[1][r]), fmaxf(s[2][r], s[3][r]));
            mx = fmaxf(mx, __shfl_xor(mx, 1));
            mx = fmaxf(mx, __shfl_xor(mx, 2));
            mx = fmaxf(mx, __shfl_xor(mx, 4));
            mx = fmaxf(mx, __shfl_xor(mx, 8));
            if (__ballot(mx > mrow[r])) {       // T13, THR=0: bit-exact skip
                float mn = fmaxf(mrow[r], mx);
                float alpha = __builtin_amdgcn_exp2f(mrow[r] - mn);
                mrow[r] = mn;
                lacc[r] *= alpha;
                o[0][r] *= alpha; o[1][r] *= alpha; o[2][r] *= alpha; o[3][r] *= alpha;
            }
#pragma unroll
            for (int ct = 0; ct < 4; ++ct) {
                float p = __builtin_amdgcn_exp2f(s[ct][r] - mrow[r]);
                Ps[w][lg * 4 + r][ct * 16 + lr] = __float2bfloat16(p);
            }
        }
        // PV + row-sum via ones-column (wave-internal LDS RAW, in-order)
#pragma unroll
        for (int kc = 0; kc < 2; ++kc) {
            bf16x8 pa = *(const bf16x8*)&Ps[w][lr][kc * 32 + lg * 8];
            lacc = __builtin_amdgcn_mfma_f32_16x16x32_bf16(pa, ones, lacc, 0, 0, 0);
#pragma unroll
            for (int ht = 0; ht < 4; ++ht) {
                bf16x8 vb = *(const bf16x8*)(VsB + SWZ(ht * 16 + lr, kc * 64 + lg * 16));
                o[ht] = __builtin_amdgcn_mfma_f32_16x16x32_bf16(pa, vb, o[ht], 0, 0, 0);
            }
        }
    }
    const int b = bh >> 4, h = bh & 15;
#pragma unroll
    for (int r = 0; r < 4; ++r) {
        float inv = 1.f / lacc[r];
        int q = qw + lg * 4 + r;
        __hip_bfloat16* yp = Y + ((size_t)b * TSEQ + q) * CEMB + h * HS + lr;
#pragma unroll
        for (int ht = 0; ht < 4; ++ht) yp[ht * 16] = __float2bfloat16(o[ht][r] * inv);
    }
}

// ---------------- Output projection, bf16 MFMA ----------------
__global__ __launch_bounds__(256) void proj_mfma_k(
    const __hip_bfloat16* __restrict__ Ab, const __hip_bfloat16* __restrict__ Wt,
    const float* __restrict__ bias, float* __restrict__ out)
{
    __shared__ __hip_bfloat16 Al[128 * 32];
    __shared__ __hip_bfloat16 Bl[128 * 32];
    const int tid = threadIdx.x;
    const int lane = tid & 63, w = tid >> 6;
    const int lr = lane & 15, lg = lane >> 4;
    const int wm = w >> 1, wn = w & 1;
    const int n0 = blockIdx.x * 128;
    const int m0 = blockIdx.y * 128;
    const __hip_bfloat16* gA = Ab + (size_t)(m0 + (tid >> 2)) * CEMB + (tid & 3) * 8;
    const __hip_bfloat16* gB = Wt + (size_t)(n0 + (tid >> 2)) * CEMB + (tid & 3) * 8;
    __hip_bfloat16* lA = &Al[tid * 8];
    __hip_bfloat16* lB = &Bl[tid * 8];
    f32x4 acc[4][4] = {};
    for (int k0 = 0; k0 < CEMB; k0 += 32) {
        if (k0) __syncthreads();
        gload16(gA + k0, lA);
        gload16(gA + 64 * CEMB + k0, lA + 2048);
        gload16(gB + k0, lB);
        gload16(gB + 64 * CEMB + k0, lB + 2048);
        __syncthreads();
        bf16x8 af[4], bfr[4];
#pragma unroll
        for (int mi = 0; mi < 4; ++mi)
            af[mi] = *(const bf16x8*)&Al[(wm * 64 + mi * 16 + lr) * 32 + lg * 8];
#pragma unroll
        for (int ni = 0; ni < 4; ++ni)
            bfr[ni] = *(const bf16x8*)&Bl[(wn * 64 + ni * 16 + lr) * 32 + lg * 8];
#pragma unroll
        for (int mi = 0; mi < 4; ++mi)
#pragma unroll
            for (int ni = 0; ni < 4; ++ni)
                acc[mi][ni] = __builtin_amdgcn_mfma_f32_16x16x32_bf16(af[mi], bfr[ni], acc[mi][ni], 0, 0, 0);
    }
#pragma unroll
    for (int mi = 0; mi < 4; ++mi) {
#pragma unroll
        for (int ni = 0; ni < 4; ++ni) {
            const int gcol = n0 + wn * 64 + ni * 16 + lr;
            const float bv = bias[gcol];
            const int growb = m0 + wm * 64 + mi * 16 + lg * 4;
#pragma unroll
            for (int r = 0; r < 4; ++r)
                out[(size_t)(growb + r) * CEMB + gcol] = acc[mi][ni][r] + bv;
        }
    }
}

extern "C" void kernel_launch(void* const* d_in, const int* in_sizes, int n_in,
                              void* d_out, int out_size, void* d_ws, size_t ws_size,
                              hipStream_t stream)
{
    const float* x      = (const float*)d_in[0];
    const float* w_attn = (const float*)d_in[1];
    const float* b_attn = (const float*)d_in[2];
    const float* w_proj = (const float*)d_in[3];
    const float* b_proj = (const float*)d_in[4];
    float* out = (float*)d_out;
    char* base = (char*)d_ws;

    const size_t MB = 1048576;
    float* tbl          = (float*)base;                         // 4 KB
    __hip_bfloat16* Xb  = (__hip_bfloat16*)(base + 4096);       // 8 MB (reused as Yb)
    __hip_bfloat16* Wta = (__hip_bfloat16*)(base + 4096 + 8 * MB);   // 6 MB
    __hip_bfloat16* Wpt = (__hip_bfloat16*)(base + 4096 + 14 * MB);  // 2 MB
    __hip_bfloat16* Qb  = (__hip_bfloat16*)(base + 4096 + 16 * MB);  // 8 MB
    __hip_bfloat16* Kb  = (__hip_bfloat16*)(base + 4096 + 24 * MB);  // 8 MB
    __hip_bfloat16* Vtb = (__hip_bfloat16*)(base + 4096 + 32 * MB);  // 8 MB
    __hip_bfloat16* Yb  = Xb;   // x no longer needed after qkv GEMM

    rope_tbl_k<<<1, 512, 0, stream>>>(tbl);
    cvt_bf16_k<<<2048, 256, 0, stream>>>(x, Xb);
    transpose_bf16_k<<<dim3(96, 32), 256, 0, stream>>>(w_attn, Wta, CEMB, 3 * CEMB);
    transpose_bf16_k<<<dim3(32, 32), 256, 0, stream>>>(w_proj, Wpt, CEMB, CEMB);
    qkv_mfma_k<<<dim3(24, 32), 256, 0, stream>>>(Xb, Wta, b_attn, tbl, Qb, Kb, Vtb);
    attn_k<<<1024, 256, 0, stream>>>(Qb, Kb, Vtb, Yb);
    proj_mfma_k<<<dim3(8, 32), 256, 0, stream>>>(Yb, Wpt, b_proj, out);
}

// Round 6
// 149.437 us; speedup vs baseline: 1.4047x; 1.0424x over previous
//
#include <hip/hip_runtime.h>
#include <hip/hip_bf16.h>
#include <math.h>

#define TSEQ 2048
#define CEMB 1024
#define NHEAD 16
#define HS 64

typedef __attribute__((ext_vector_type(8))) short bf16x8;
typedef __attribute__((ext_vector_type(4))) float f32x4;

__device__ __forceinline__ void gload16(const void* g, void* l) {
    __builtin_amdgcn_global_load_lds(
        (const __attribute__((address_space(1))) unsigned int*)g,
        (__attribute__((address_space(3))) unsigned int*)l, 16, 0, 0);
}

// swizzled LDS byte offset for [row][col] bf16 tiles with 128 B rows
#define SWZ(row, colb) (((((row) << 7) + (colb))) ^ (((row) & 7) << 4))

// ---------------- RoPE table ----------------
// Reference quirk: _apply_rope uses cache[:d1] where d1 = n_head after the
// transpose, so the rotation angle is head_index * theta_j (constant over t).
__global__ void rope_tbl_k(float* __restrict__ tbl) {
    int i = blockIdx.x * blockDim.x + threadIdx.x;
    if (i >= NHEAD * 32) return;
    int h = i >> 5, j = i & 31;
    double theta = pow(10000.0, -2.0 * (double)j / 1024.0);
    double ang = (double)h * theta;
    tbl[2 * i + 0] = (float)cos(ang);
    tbl[2 * i + 1] = (float)sin(ang);
}

// ---------------- fp32 -> bf16 convert (x) ----------------
__global__ __launch_bounds__(256) void cvt_bf16_k(const float* __restrict__ in,
                                                  __hip_bfloat16* __restrict__ out) {
    int i = (blockIdx.x * 256 + threadIdx.x) * 8;
    float4 a = *(const float4*)(in + i);
    float4 b = *(const float4*)(in + i + 4);
    union { bf16x8 v; __hip_bfloat16 h[8]; } pk;
    pk.h[0] = __float2bfloat16(a.x); pk.h[1] = __float2bfloat16(a.y);
    pk.h[2] = __float2bfloat16(a.z); pk.h[3] = __float2bfloat16(a.w);
    pk.h[4] = __float2bfloat16(b.x); pk.h[5] = __float2bfloat16(b.y);
    pk.h[6] = __float2bfloat16(b.z); pk.h[7] = __float2bfloat16(b.w);
    *(bf16x8*)(out + i) = pk.v;
}

// ---------------- transpose fp32 (K,N) -> bf16 (N,K) ----------------
__global__ __launch_bounds__(256) void transpose_bf16_k(const float* __restrict__ src,
                                                        __hip_bfloat16* __restrict__ dst,
                                                        int K, int N) {
    __shared__ float tile[32][33];
    int n0 = blockIdx.x * 32, k0 = blockIdx.y * 32;
    int tx = threadIdx.x & 31, ty = threadIdx.x >> 5;   // ty 0..7
#pragma unroll
    for (int i = 0; i < 32; i += 8)
        tile[ty + i][tx] = src[(size_t)(k0 + ty + i) * N + n0 + tx];
    __syncthreads();
#pragma unroll
    for (int i = 0; i < 32; i += 8)
        dst[(size_t)(n0 + ty + i) * K + k0 + tx] = __float2bfloat16(tile[tx][ty + i]);
}

// ---------------- QKV GEMM, bf16 MFMA, RoPE epilogue ----------------
// 128x128 tile, 4 waves (2x2), 4x4 16x16x32 frags, BK=32, double-buffered
// global_load_lds prefetch (issue t+1, compute t, ONE barrier per step).
__global__ __launch_bounds__(256) void qkv_mfma_k(
    const __hip_bfloat16* __restrict__ Xb, const __hip_bfloat16* __restrict__ Wt,
    const float* __restrict__ bias, const float* __restrict__ tbl,
    __hip_bfloat16* __restrict__ Qb, __hip_bfloat16* __restrict__ Kb,
    __hip_bfloat16* __restrict__ Vtb)
{
    __shared__ __hip_bfloat16 Al[2][128 * 32];
    __shared__ __hip_bfloat16 Bl[2][128 * 32];
    const int tid = threadIdx.x;
    const int lane = tid & 63, w = tid >> 6;
    const int lr = lane & 15, lg = lane >> 4;
    const int wm = w >> 1, wn = w & 1;
    const int n0 = blockIdx.x * 128;   // 0..2944
    const int m0 = blockIdx.y * 128;   // 0..3968
    const __hip_bfloat16* gA = Xb + (size_t)(m0 + (tid >> 2)) * CEMB + (tid & 3) * 8;
    const __hip_bfloat16* gB = Wt + (size_t)(n0 + (tid >> 2)) * CEMB + (tid & 3) * 8;
#define QSTAGE(buf, kk) do { \
        gload16(gA + (kk), &Al[buf][tid * 8]); \
        gload16(gA + 64 * CEMB + (kk), &Al[buf][2048 + tid * 8]); \
        gload16(gB + (kk), &Bl[buf][tid * 8]); \
        gload16(gB + 64 * CEMB + (kk), &Bl[buf][2048 + tid * 8]); } while (0)
    f32x4 acc[4][4] = {};
    QSTAGE(0, 0);
    __syncthreads();
    for (int k0 = 0; k0 < CEMB; k0 += 32) {
        const int cur = (k0 >> 5) & 1;
        if (k0 + 32 < CEMB) QSTAGE(cur ^ 1, k0 + 32);
        bf16x8 af[4], bfr[4];
#pragma unroll
        for (int mi = 0; mi < 4; ++mi)
            af[mi] = *(const bf16x8*)&Al[cur][(wm * 64 + mi * 16 + lr) * 32 + lg * 8];
#pragma unroll
        for (int ni = 0; ni < 4; ++ni)
            bfr[ni] = *(const bf16x8*)&Bl[cur][(wn * 64 + ni * 16 + lr) * 32 + lg * 8];
#pragma unroll
        for (int mi = 0; mi < 4; ++mi)
#pragma unroll
            for (int ni = 0; ni < 4; ++ni)
                acc[mi][ni] = __builtin_amdgcn_mfma_f32_16x16x32_bf16(af[mi], bfr[ni], acc[mi][ni], 0, 0, 0);
        __syncthreads();
    }
    // epilogue: bias + rope + scatter. sec/bb uniform per block.
    const int sec = (n0 >> 10);
#pragma unroll
    for (int mi = 0; mi < 4; ++mi) {
#pragma unroll
        for (int ni = 0; ni < 4; ++ni) {
            const int gcol = n0 + wn * 64 + ni * 16 + lr;
            const int c63 = gcol & 63;
            const int h = (gcol & 1023) >> 6;
            const int j = c63 >> 1;
            const float cth = tbl[(h * 32 + j) * 2 + 0];
            const float sth = tbl[(h * 32 + j) * 2 + 1];
            const float bv = bias[gcol];
            const int growb = m0 + wm * 64 + mi * 16 + lg * 4;
            const int bb = growb >> 11;
            const int t0 = growb & 2047;
            if (sec == 2) {
                union { unsigned long long u; __hip_bfloat16 hh[4]; } pk;
#pragma unroll
                for (int r = 0; r < 4; ++r) pk.hh[r] = __float2bfloat16(acc[mi][ni][r] + bv);
                *(unsigned long long*)&Vtb[(((size_t)bb * NHEAD + h) * HS + c63) * TSEQ + t0] = pk.u;
            } else {
                // Q scale folds 1/sqrt(hs) AND log2(e) so attention can use exp2
                const float sc = (sec == 0) ? 0.18033688011112042f : 1.0f;
                __hip_bfloat16* dst = (sec == 0) ? Qb : Kb;
#pragma unroll
                for (int r = 0; r < 4; ++r) {
                    float val = acc[mi][ni][r] + bv;
                    float prt = __shfl_xor(val, 1);
                    float rot = (lr & 1) ? (val * cth + prt * sth) : (val * cth - prt * sth);
                    dst[(((size_t)bb * NHEAD + h) * TSEQ + t0 + r) * HS + c63] = __float2bfloat16(rot * sc);
                }
            }
        }
    }
#undef QSTAGE
}

// ---------------- Flash attention, bf16 MFMA ----------------
// Flat 1D grid: bh = id&31 (CU-balance + per-XCD K/V locality), qblk = id>>5.
// Double-buffered K/V staging: issue gload_lds for kt+1 into buf^1, compute kt,
// single barrier per tile (vmcnt drain hidden under compute). Pre-swizzled
// global source, linear LDS dest, swizzled read (T21). Always-rescale
// (exp2(0)=1 -> bit-exact, no ballot/branch). Ones-column MFMA row-sum.
__global__ __launch_bounds__(256) void attn_k(
    const __hip_bfloat16* __restrict__ Q, const __hip_bfloat16* __restrict__ K,
    const __hip_bfloat16* __restrict__ Vt, __hip_bfloat16* __restrict__ Y)
{
    __shared__ __hip_bfloat16 KsBuf[2][64 * 64];   // [kv][hs], swizzled storage
    __shared__ __hip_bfloat16 VsBuf[2][64 * 64];   // [hs][kv], swizzled storage
    __shared__ __hip_bfloat16 Ps[4][16][72];       // per-wave P, [q][kv]
    const int tid = threadIdx.x;
    const int w = tid >> 6;
    const int lane = tid & 63;
    const int lr = lane & 15;
    const int lg = lane >> 4;
    const int id = blockIdx.x;
    const int bh = id & 31;          // fast dim: decorrelates qblk from CU
    const int qblk = id >> 5;
    const size_t bho = (size_t)bh * TSEQ * HS;
    const int qw = qblk * 64 + w * 16;

    // staging: 512 16B chunks per tile; thread t owns chunks t and t+256.
    // LDS dest linear; global source pre-permuted by the inverse XOR swizzle.
    const __hip_bfloat16* Kg = K + bho;
    const __hip_bfloat16* Vg = Vt + bho;
    int ko0, ko1, vo0, vo1;
    {
        int o0 = tid * 16, o1 = o0 + 4096;
        int L0 = o0 ^ (((o0 >> 7) & 7) << 4);
        int L1 = o1 ^ (((o1 >> 7) & 7) << 4);
        ko0 = (L0 >> 7) * HS + ((L0 & 127) >> 1);
        ko1 = (L1 >> 7) * HS + ((L1 & 127) >> 1);
        vo0 = (L0 >> 7) * TSEQ + ((L0 & 127) >> 1);
        vo1 = (L1 >> 7) * TSEQ + ((L1 & 127) >> 1);
    }
#define ASTAGE(buf, kt_) do { \
        const __hip_bfloat16* kg_ = Kg + (size_t)(kt_) * 64 * HS; \
        const __hip_bfloat16* vg_ = Vg + (size_t)(kt_) * 64; \
        char* kb_ = (char*)KsBuf[buf]; char* vb_ = (char*)VsBuf[buf]; \
        gload16(kg_ + ko0, kb_ + tid * 16); \
        gload16(kg_ + ko1, kb_ + 4096 + tid * 16); \
        gload16(vg_ + vo0, vb_ + tid * 16); \
        gload16(vg_ + vo1, vb_ + 4096 + tid * 16); } while (0)

    bf16x8 qa[2];
    {
        const __hip_bfloat16* qp = Q + bho + (size_t)(qw + lr) * HS + lg * 8;
        qa[0] = *(const bf16x8*)(qp);
        qa[1] = *(const bf16x8*)(qp + 32);
    }
    const bf16x8 ones = {0x3F80, 0x3F80, 0x3F80, 0x3F80, 0x3F80, 0x3F80, 0x3F80, 0x3F80};
    float mrow[4] = {-1e30f, -1e30f, -1e30f, -1e30f};
    f32x4 lacc = {};
    f32x4 o[4] = {};   // [ht]: col = ht*16+lr, row(q) = qw + lg*4 + r

    ASTAGE(0, 0);
    __syncthreads();
    for (int kt = 0; kt <= qblk; ++kt) {
        const int cur = kt & 1;
        if (kt < qblk) ASTAGE(cur ^ 1, kt + 1);   // loads fly under this tile's compute
        char* KsB = (char*)KsBuf[cur];
        char* VsB = (char*)VsBuf[cur];
        // S = Q K^T  (Q pre-scaled by 0.125*log2e)
        f32x4 s[4] = {};
#pragma unroll
        for (int ct = 0; ct < 4; ++ct) {
#pragma unroll
            for (int kb = 0; kb < 2; ++kb) {
                bf16x8 kf = *(const bf16x8*)(KsB + SWZ(ct * 16 + lr, kb * 64 + lg * 16));
                s[ct] = __builtin_amdgcn_mfma_f32_16x16x32_bf16(qa[kb], kf, s[ct], 0, 0, 0);
            }
        }
        if (kt == qblk) {
#pragma unroll
            for (int ct = 0; ct < 4; ++ct) {
                int col = kt * 64 + ct * 16 + lr;
#pragma unroll
                for (int r = 0; r < 4; ++r) {
                    if (col > qw + lg * 4 + r) s[ct][r] = -1e30f;
                }
            }
        }
        // online softmax (log2 domain); row r lives in 16 lanes (fixed lg).
        // Unconditional rescale: exp2(0)=1.0 when max unchanged -> bit-exact.
#pragma unroll
        for (int r = 0; r < 4; ++r) {
            float mx = fmaxf(fmaxf(s[0][r], s[1][r]), fmaxf(s[2][r], s[3][r]));
            mx = fmaxf(mx, __shfl_xor(mx, 1));
            mx = fmaxf(mx, __shfl_xor(mx, 2));
            mx = fmaxf(mx, __shfl_xor(mx, 4));
            mx = fmaxf(mx, __shfl_xor(mx, 8));
            float mn = fmaxf(mrow[r], mx);
            float alpha = __builtin_amdgcn_exp2f(mrow[r] - mn);
            mrow[r] = mn;
            lacc[r] *= alpha;
            o[0][r] *= alpha; o[1][r] *= alpha; o[2][r] *= alpha; o[3][r] *= alpha;
#pragma unroll
            for (int ct = 0; ct < 4; ++ct) {
                float p = __builtin_amdgcn_exp2f(s[ct][r] - mn);
                Ps[w][lg * 4 + r][ct * 16 + lr] = __float2bfloat16(p);
            }
        }
        // PV + row-sum via ones-column (wave-internal LDS RAW, in-order)
#pragma unroll
        for (int kc = 0; kc < 2; ++kc) {
            bf16x8 pa = *(const bf16x8*)&Ps[w][lr][kc * 32 + lg * 8];
            lacc = __builtin_amdgcn_mfma_f32_16x16x32_bf16(pa, ones, lacc, 0, 0, 0);
#pragma unroll
            for (int ht = 0; ht < 4; ++ht) {
                bf16x8 vb = *(const bf16x8*)(VsB + SWZ(ht * 16 + lr, kc * 64 + lg * 16));
                o[ht] = __builtin_amdgcn_mfma_f32_16x16x32_bf16(pa, vb, o[ht], 0, 0, 0);
            }
        }
        __syncthreads();   // drains prefetch vmcnt + guards buffer reuse
    }
    const int b = bh >> 4, h = bh & 15;
#pragma unroll
    for (int r = 0; r < 4; ++r) {
        float inv = 1.f / lacc[r];
        int q = qw + lg * 4 + r;
        __hip_bfloat16* yp = Y + ((size_t)b * TSEQ + q) * CEMB + h * HS + lr;
#pragma unroll
        for (int ht = 0; ht < 4; ++ht) yp[ht * 16] = __float2bfloat16(o[ht][r] * inv);
    }
#undef ASTAGE
}

// ---------------- Output projection, bf16 MFMA ----------------
__global__ __launch_bounds__(256) void proj_mfma_k(
    const __hip_bfloat16* __restrict__ Ab, const __hip_bfloat16* __restrict__ Wt,
    const float* __restrict__ bias, float* __restrict__ out)
{
    __shared__ __hip_bfloat16 Al[2][128 * 32];
    __shared__ __hip_bfloat16 Bl[2][128 * 32];
    const int tid = threadIdx.x;
    const int lane = tid & 63, w = tid >> 6;
    const int lr = lane & 15, lg = lane >> 4;
    const int wm = w >> 1, wn = w & 1;
    const int n0 = blockIdx.x * 128;
    const int m0 = blockIdx.y * 128;
    const __hip_bfloat16* gA = Ab + (size_t)(m0 + (tid >> 2)) * CEMB + (tid & 3) * 8;
    const __hip_bfloat16* gB = Wt + (size_t)(n0 + (tid >> 2)) * CEMB + (tid & 3) * 8;
#define PSTAGE(buf, kk) do { \
        gload16(gA + (kk), &Al[buf][tid * 8]); \
        gload16(gA + 64 * CEMB + (kk), &Al[buf][2048 + tid * 8]); \
        gload16(gB + (kk), &Bl[buf][tid * 8]); \
        gload16(gB + 64 * CEMB + (kk), &Bl[buf][2048 + tid * 8]); } while (0)
    f32x4 acc[4][4] = {};
    PSTAGE(0, 0);
    __syncthreads();
    for (int k0 = 0; k0 < CEMB; k0 += 32) {
        const int cur = (k0 >> 5) & 1;
        if (k0 + 32 < CEMB) PSTAGE(cur ^ 1, k0 + 32);
        bf16x8 af[4], bfr[4];
#pragma unroll
        for (int mi = 0; mi < 4; ++mi)
            af[mi] = *(const bf16x8*)&Al[cur][(wm * 64 + mi * 16 + lr) * 32 + lg * 8];
#pragma unroll
        for (int ni = 0; ni < 4; ++ni)
            bfr[ni] = *(const bf16x8*)&Bl[cur][(wn * 64 + ni * 16 + lr) * 32 + lg * 8];
#pragma unroll
        for (int mi = 0; mi < 4; ++mi)
#pragma unroll
            for (int ni = 0; ni < 4; ++ni)
                acc[mi][ni] = __builtin_amdgcn_mfma_f32_16x16x32_bf16(af[mi], bfr[ni], acc[mi][ni], 0, 0, 0);
        __syncthreads();
    }
#pragma unroll
    for (int mi = 0; mi < 4; ++mi) {
#pragma unroll
        for (int ni = 0; ni < 4; ++ni) {
            const int gcol = n0 + wn * 64 + ni * 16 + lr;
            const float bv = bias[gcol];
            const int growb = m0 + wm * 64 + mi * 16 + lg * 4;
#pragma unroll
            for (int r = 0; r < 4; ++r)
                out[(size_t)(growb + r) * CEMB + gcol] = acc[mi][ni][r] + bv;
        }
    }
#undef PSTAGE
}

extern "C" void kernel_launch(void* const* d_in, const int* in_sizes, int n_in,
                              void* d_out, int out_size, void* d_ws, size_t ws_size,
                              hipStream_t stream)
{
    const float* x      = (const float*)d_in[0];
    const float* w_attn = (const float*)d_in[1];
    const float* b_attn = (const float*)d_in[2];
    const float* w_proj = (const float*)d_in[3];
    const float* b_proj = (const float*)d_in[4];
    float* out = (float*)d_out;
    char* base = (char*)d_ws;

    const size_t MB = 1048576;
    float* tbl          = (float*)base;                         // 4 KB
    __hip_bfloat16* Xb  = (__hip_bfloat16*)(base + 4096);       // 8 MB (reused as Yb)
    __hip_bfloat16* Wta = (__hip_bfloat16*)(base + 4096 + 8 * MB);   // 6 MB
    __hip_bfloat16* Wpt = (__hip_bfloat16*)(base + 4096 + 14 * MB);  // 2 MB
    __hip_bfloat16* Qb  = (__hip_bfloat16*)(base + 4096 + 16 * MB);  // 8 MB
    __hip_bfloat16* Kb  = (__hip_bfloat16*)(base + 4096 + 24 * MB);  // 8 MB
    __hip_bfloat16* Vtb = (__hip_bfloat16*)(base + 4096 + 32 * MB);  // 8 MB
    __hip_bfloat16* Yb  = Xb;   // x no longer needed after qkv GEMM

    rope_tbl_k<<<1, 512, 0, stream>>>(tbl);
    cvt_bf16_k<<<2048, 256, 0, stream>>>(x, Xb);
    transpose_bf16_k<<<dim3(96, 32), 256, 0, stream>>>(w_attn, Wta, CEMB, 3 * CEMB);
    transpose_bf16_k<<<dim3(32, 32), 256, 0, stream>>>(w_proj, Wpt, CEMB, CEMB);
    qkv_mfma_k<<<dim3(24, 32), 256, 0, stream>>>(Xb, Wta, b_attn, tbl, Qb, Kb, Vtb);
    attn_k<<<1024, 256, 0, stream>>>(Qb, Kb, Vtb, Yb);
    proj_mfma_k<<<dim3(8, 32), 256, 0, stream>>>(Yb, Wpt, b_proj, out);
}